// Round 15
// baseline (122.801 us; speedup 1.0000x reference)
//
#include <hip/hip_runtime.h>
#include <math.h>

#define BATCH 4
#define SEQ   4096
#define DIM   1024
#define HEAD  64
#define MROWS (BATCH*SEQ)   // 16384
#define NCOL  192
#define WST   1040          // repacked W row stride (elements)
#define KT    64
#define QBLK  64            // flashmm q-rows per block (proven locality)
#define BK2   64            // qkvmm K-step
#define NIT2  (DIM / BK2)   // 16

typedef __attribute__((ext_vector_type(8))) short short8;
typedef __attribute__((ext_vector_type(4))) float f32x4;

static __device__ __forceinline__ unsigned short f2b(float f) {
    union { float f; unsigned u; } v; v.f = f;
    return (unsigned short)((v.u + 0x7FFFu + ((v.u >> 16) & 1u)) >> 16);
}
// hardware RTNE pack: low16 = bf16(a), high16 = bf16(b)
static __device__ __forceinline__ unsigned cvtpk(float a, float b) {
    unsigned r;
    asm("v_cvt_pk_bf16_f32 %0, %1, %2" : "=v"(r) : "v"(a), "v"(b));
    return r;
}

// ---------------- Kernel 0: weight convert fp32 -> bf16, stride-1040 repack ----------------
#define QSC (0.125f * 1.4426950408889634f)   // fold 1/sqrt(64) * log2(e): exp2 domain
__global__ __launch_bounds__(256) void wconv_kernel(
    const float* __restrict__ wq, const float* __restrict__ bq,
    const float* __restrict__ wk, const float* __restrict__ bk,
    const float* __restrict__ wv, const float* __restrict__ bv,
    unsigned short* __restrict__ Wb, float* __restrict__ biasAll)
{
    int idx = blockIdx.x * 256 + threadIdx.x;
    int e   = idx * 4;
    int row = e >> 10;
    int col = e & 1023;
    const float* src = (row < 64) ? wq : (row < 128) ? wk : wv;
    float s = (row < 64) ? QSC : 1.0f;
    float4 g = *(const float4*)&src[(size_t)(row & 63) * DIM + col];
    ushort4 o;
    o.x = f2b(g.x * s); o.y = f2b(g.y * s); o.z = f2b(g.z * s); o.w = f2b(g.w * s);
    *(ushort4*)&Wb[(size_t)row * WST + col] = o;
    if (idx < 192) {
        const float* bs = (idx < 64) ? bq : (idx < 128) ? bk : bv;
        biasAll[idx] = bs[idx & 63] * ((idx < 64) ? QSC : 1.0f);
    }
}

// ---------------- Kernel 1: fused QKV projection (R13-exact, best known: 40.6us) ----------
__global__ __launch_bounds__(256, 4) void qkvmm_kernel(
    const float* __restrict__ x, const unsigned short* __restrict__ Wb,
    const float* __restrict__ biasAll,
    unsigned short* __restrict__ qout, unsigned short* __restrict__ kout,
    unsigned short* __restrict__ vtout)
{
    __shared__ unsigned short xs[32 * BK2];     // 4 KB
    __shared__ unsigned short ws[NCOL * BK2];   // 24 KB

    const int tid  = threadIdx.x;
    const int m0   = blockIdx.x * 32;
    const int bb   = m0 >> 12;
    const int lane = tid & 63;
    const int w    = tid >> 6;
    const int lr   = lane & 15;
    const int lg   = lane >> 4;
    const int mrow  = (w >> 1) * 16;
    const int nbase = (w & 1) * 6;

    int wrow[6], wc[6];
    #pragma unroll
    for (int j = 0; j < 6; ++j) { int L = j * 256 + tid; wrow[j] = L >> 3; wc[j] = L & 7; }
    const int xr = tid >> 2, xq = tid & 3;

    f32x4 acc[6];
    #pragma unroll
    for (int nt = 0; nt < 6; ++nt) acc[nt] = (f32x4){0.f, 0.f, 0.f, 0.f};

    float4 xg[4];
    short8 wg[6];

    auto LOADR = [&](int ko) {
        if (tid < 128) {
            const float* xp = &x[(size_t)(m0 + xr) * DIM + ko + xq * 16];
            xg[0] = *(const float4*)xp;       xg[1] = *(const float4*)(xp + 4);
            xg[2] = *(const float4*)(xp + 8); xg[3] = *(const float4*)(xp + 12);
        }
        #pragma unroll
        for (int j = 0; j < 6; ++j)
            wg[j] = *(const short8*)&Wb[(size_t)wrow[j] * WST + ko + wc[j] * 8];
    };
    auto WRITE = [&]() {
        if (tid < 128) {
            uint4 c0, c1;
            c0.x = cvtpk(xg[0].x, xg[0].y); c0.y = cvtpk(xg[0].z, xg[0].w);
            c0.z = cvtpk(xg[1].x, xg[1].y); c0.w = cvtpk(xg[1].z, xg[1].w);
            c1.x = cvtpk(xg[2].x, xg[2].y); c1.y = cvtpk(xg[2].z, xg[2].w);
            c1.z = cvtpk(xg[3].x, xg[3].y); c1.w = cvtpk(xg[3].z, xg[3].w);
            *(uint4*)&xs[xr * BK2 + (((2 * xq)     ^ (xr & 7)) * 8)] = c0;
            *(uint4*)&xs[xr * BK2 + (((2 * xq + 1) ^ (xr & 7)) * 8)] = c1;
        }
        #pragma unroll
        for (int j = 0; j < 6; ++j)
            *(short8*)&ws[wrow[j] * BK2 + ((wc[j] ^ (wrow[j] & 7)) * 8)] = wg[j];
    };

    LOADR(0);
    for (int it = 0; it < NIT2; ++it) {
        __syncthreads();
        WRITE();
        __syncthreads();
        if (it + 1 < NIT2) LOADR((it + 1) * BK2);

        __builtin_amdgcn_s_setprio(1);
        #pragma unroll
        for (int h = 0; h < 2; ++h) {
            const int arow = mrow + lr;
            short8 af = *(const short8*)&xs[arow * BK2 + (((h * 4 + lg) ^ (arow & 7)) * 8)];
            #pragma unroll
            for (int nt = 0; nt < 6; ++nt) {
                int n = (nbase + nt) * 16 + lr;
                short8 bf = *(const short8*)&ws[n * BK2 + (((h * 4 + lg) ^ (n & 7)) * 8)];
                acc[nt] = __builtin_amdgcn_mfma_f32_16x16x32_bf16(af, bf, acc[nt], 0, 0, 0);
            }
        }
        __builtin_amdgcn_s_setprio(0);
    }

    #pragma unroll
    for (int nt = 0; nt < 6; ++nt) {
        int gn = (nbase + nt) * 16 + lr;
        float bv_ = biasAll[gn];
        #pragma unroll
        for (int r = 0; r < 4; ++r) {
            int grow = m0 + mrow + lg * 4 + r;
            unsigned short val = f2b(acc[nt][r] + bv_);
            if (gn < 64)       qout[(size_t)grow * HEAD + gn] = val;
            else if (gn < 128) kout[(size_t)grow * HEAD + gn - 64] = val;
            else {
                int t = (m0 & 4095) + mrow + lg * 4 + r;
                vtout[((size_t)bb * HEAD + gn - 128) * SEQ + t] = val;
            }
        }
    }
}

// ---------------- Kernel 2: flash attention — 2-wave blocks, 32 q-rows/wave ----------------
// grid (SEQ/QBLK, BATCH, KS), block 128 (2 waves). Wave w owns q-rows t0+w*32+u*16+lr
// (u=0,1). K-frags and V-frags are loaded ONCE per wave and reused across both u
// sub-tiles -> per-tile LDS read traffic drops ~33% vs the 4-wave version.
__global__ __launch_bounds__(128, 3) void flashmm_kernel(
    const unsigned short* __restrict__ qb, const unsigned short* __restrict__ kb,
    const unsigned short* __restrict__ vt, const int* __restrict__ mask,
    float* __restrict__ opart, float* __restrict__ mpart, float* __restrict__ lpart,
    int nsplit)
{
    const int b  = blockIdx.y;
    const int t0 = blockIdx.x * QBLK;
    const int z  = blockIdx.z;
    const int tid  = threadIdx.x;
    const int lane = tid & 63;
    const int w    = tid >> 6;          // 0..1
    const int lr = lane & 15;
    const int lg = lane >> 4;
    const int span = SEQ / nsplit;
    const int s_begin = z * span, s_end = s_begin + span;

    __shared__ unsigned short ks_l[KT * HEAD];        // 8 KB
    __shared__ unsigned short vt_l[HEAD * KT];        // 8 KB
    __shared__ unsigned short ps_l[2][2][16 * KT];    // 8 KB  [wave][u]
    __shared__ float mkf[KT];

    // Q fragments: wave w, sub-tile u -> rows t0 + w*32 + u*16 + lr
    short8 qf[2][2];
    #pragma unroll
    for (int u = 0; u < 2; ++u) {
        const unsigned short* qrow =
            qb + ((size_t)(b * SEQ + t0 + w * 32 + u * 16 + lr)) * HEAD;
        qf[u][0] = *(const short8*)(qrow + lg * 8);
        qf[u][1] = *(const short8*)(qrow + 32 + lg * 8);
    }

    f32x4 acc_o[2][4];
    #pragma unroll
    for (int u = 0; u < 2; ++u)
        #pragma unroll
        for (int nt = 0; nt < 4; ++nt) acc_o[u][nt] = (f32x4){0.f, 0.f, 0.f, 0.f};
    float m_r[2] = {-INFINITY, -INFINITY};
    float l_r[2] = {0.f, 0.f};

    short8 kg[4], vg[4];
    float mgf = 0.f;

    auto LOADR = [&](int st) {
        #pragma unroll
        for (int i = 0; i < 4; ++i) {
            int c   = tid + i * 128;          // 0..511 chunks
            int row = c >> 3;
            int h0  = (c & 7) * 8;
            kg[i] = *(const short8*)(kb + ((size_t)(b * SEQ + st + row)) * HEAD + h0);
            vg[i] = *(const short8*)(vt + ((size_t)(b * HEAD + row)) * SEQ + st + h0);
        }
        if (tid < KT) mgf = (mask[(size_t)b * SEQ + st + tid] != 0) ? 0.f : -1e9f;
    };
    auto WRITE = [&]() {
        #pragma unroll
        for (int i = 0; i < 4; ++i) {
            int c   = tid + i * 128;
            int row = c >> 3;
            int h0  = (c & 7) * 8;
            *(short8*)&ks_l[row * HEAD + (h0 ^ ((row & 7) << 3))] = kg[i];
            *(short8*)&vt_l[row * KT + (h0 ^ ((row & 7) << 3))] = vg[i];
        }
        if (tid < KT) mkf[tid] = mgf;
    };

    LOADR(s_begin);
    for (int st = s_begin; st < s_end; st += KT) {
        __syncthreads();
        WRITE();
        __syncthreads();
        if (st + KT < s_end) LOADR(st + KT);

        // ---- QK^T swapped: K-frags shared across u ----
        f32x4 sT[2][4];
        __builtin_amdgcn_s_setprio(1);
        #pragma unroll
        for (int ct = 0; ct < 4; ++ct) {
            int krow = ct * 16 + lr;
            short8 kf0 = *(const short8*)&ks_l[krow * HEAD + ((lg * 8) ^ ((krow & 7) << 3))];
            short8 kf1 = *(const short8*)&ks_l[krow * HEAD + ((32 + lg * 8) ^ ((krow & 7) << 3))];
            #pragma unroll
            for (int u = 0; u < 2; ++u) {
                f32x4 zz = (f32x4){0.f, 0.f, 0.f, 0.f};
                zz = __builtin_amdgcn_mfma_f32_16x16x32_bf16(kf0, qf[u][0], zz, 0, 0, 0);
                zz = __builtin_amdgcn_mfma_f32_16x16x32_bf16(kf1, qf[u][1], zz, 0, 0, 0);
                sT[u][ct] = zz;
            }
        }
        __builtin_amdgcn_s_setprio(0);

        // ---- additive mask bias (shared across u) ----
        #pragma unroll
        for (int ct = 0; ct < 4; ++ct) {
            f32x4 mb = *(const f32x4*)&mkf[ct * 16 + lg * 4];
            #pragma unroll
            for (int u = 0; u < 2; ++u) {
                sT[u][ct][0] += mb[0]; sT[u][ct][1] += mb[1];
                sT[u][ct][2] += mb[2]; sT[u][ct][3] += mb[3];
            }
        }

        // ---- softmax per sub-tile (defer-max, exp2 domain) ----
        #pragma unroll
        for (int u = 0; u < 2; ++u) {
            float mx = sT[u][0][0];
            #pragma unroll
            for (int ct = 0; ct < 4; ++ct)
                #pragma unroll
                for (int r = 0; r < 4; ++r) mx = fmaxf(mx, sT[u][ct][r]);
            mx = fmaxf(mx, __shfl_xor(mx, 16));
            mx = fmaxf(mx, __shfl_xor(mx, 32));

            bool defer = __all(mx <= m_r[u] + 8.f);
            float base = defer ? m_r[u] : fmaxf(m_r[u], mx);

            float rs = 0.f;
            #pragma unroll
            for (int ct = 0; ct < 4; ++ct)
                #pragma unroll
                for (int r = 0; r < 4; ++r) {
                    float p = __builtin_amdgcn_exp2f(sT[u][ct][r] - base);
                    sT[u][ct][r] = p;
                    rs += p;
                }
            rs += __shfl_xor(rs, 16);
            rs += __shfl_xor(rs, 32);

            if (defer) {
                l_r[u] += rs;
            } else {
                float sf = __builtin_amdgcn_exp2f(m_r[u] - base);
                l_r[u] = l_r[u] * sf + rs;
                m_r[u] = base;
                #pragma unroll
                for (int r = 0; r < 4; ++r) {
                    float sfr = __shfl(sf, lg * 4 + r);
                    #pragma unroll
                    for (int nt = 0; nt < 4; ++nt) acc_o[u][nt][r] *= sfr;
                }
            }

            #pragma unroll
            for (int ct = 0; ct < 4; ++ct) {
                uint2 pk;
                pk.x = cvtpk(sT[u][ct][0], sT[u][ct][1]);
                pk.y = cvtpk(sT[u][ct][2], sT[u][ct][3]);
                *(uint2*)&ps_l[w][u][lr * KT + ((ct * 16 + lg * 4) ^ ((lr & 7) << 3))] = pk;
            }
        }

        // ---- PV: V-frags shared across u ----
        __builtin_amdgcn_s_setprio(1);
        #pragma unroll
        for (int kk = 0; kk < 2; ++kk) {
            int s0 = kk * 32 + lg * 8;
            short8 pf0 = *(const short8*)&ps_l[w][0][lr * KT + (s0 ^ ((lr & 7) << 3))];
            short8 pf1 = *(const short8*)&ps_l[w][1][lr * KT + (s0 ^ ((lr & 7) << 3))];
            #pragma unroll
            for (int nt = 0; nt < 4; ++nt) {
                int hrow = nt * 16 + lr;
                short8 vf = *(const short8*)&vt_l[hrow * KT + (s0 ^ ((hrow & 7) << 3))];
                acc_o[0][nt] = __builtin_amdgcn_mfma_f32_16x16x32_bf16(pf0, vf, acc_o[0][nt], 0, 0, 0);
                acc_o[1][nt] = __builtin_amdgcn_mfma_f32_16x16x32_bf16(pf1, vf, acc_o[1][nt], 0, 0, 0);
            }
        }
        __builtin_amdgcn_s_setprio(0);
    }

    // ---- write unnormalized partials ----
    #pragma unroll
    for (int u = 0; u < 2; ++u) {
        const size_t rbase = (size_t)z * MROWS + (size_t)b * SEQ + t0 + w * 32 + u * 16;
        const size_t obase = rbase * HEAD;
        #pragma unroll
        for (int nt = 0; nt < 4; ++nt)
            #pragma unroll
            for (int r = 0; r < 4; ++r) {
                int R = lg * 4 + r;
                opart[obase + (size_t)R * HEAD + nt * 16 + lr] = acc_o[u][nt][r];
            }
        if (lg == 0) {
            mpart[rbase + lr] = m_r[u];
            lpart[rbase + lr] = l_r[u];
        }
    }
}

// ---------------- Kernel 3: split combine + normalize (exp2 domain) ----------------
__global__ __launch_bounds__(256) void combine_kernel(
    const float* __restrict__ op, const float* __restrict__ mp,
    const float* __restrict__ lp, float* __restrict__ out, int nsplit)
{
    int idx = blockIdx.x * 256 + threadIdx.x;
    int row = idx >> 4;
    int h4  = (idx & 15) * 4;
    float mstar = -INFINITY;
    for (int s = 0; s < nsplit; ++s)
        mstar = fmaxf(mstar, mp[(size_t)s * MROWS + row]);
    float L = 0.f;
    float ax = 0.f, ay = 0.f, az = 0.f, aw = 0.f;
    for (int s = 0; s < nsplit; ++s) {
        float wgt = __builtin_amdgcn_exp2f(mp[(size_t)s * MROWS + row] - mstar);
        L += lp[(size_t)s * MROWS + row] * wgt;
        float4 o = *(const float4*)&op[((size_t)s * MROWS + row) * HEAD + h4];
        ax += o.x * wgt; ay += o.y * wgt; az += o.z * wgt; aw += o.w * wgt;
    }
    float r = 1.f / L;
    float4 res; res.x = ax * r; res.y = ay * r; res.z = az * r; res.w = aw * r;
    *(float4*)&out[(size_t)row * HEAD + h4] = res;
}

extern "C" void kernel_launch(void* const* d_in, const int* in_sizes, int n_in,
                              void* d_out, int out_size, void* d_ws, size_t ws_size,
                              hipStream_t stream) {
    const float* x    = (const float*)d_in[0];
    const int*   mask = (const int*)d_in[1];
    const float* wq   = (const float*)d_in[2];
    const float* bq   = (const float*)d_in[3];
    const float* wk   = (const float*)d_in[4];
    const float* bk   = (const float*)d_in[5];
    const float* wv   = (const float*)d_in[6];
    const float* bv   = (const float*)d_in[7];
    float* out = (float*)d_out;
    (void)in_sizes; (void)n_in; (void)out_size;

    const size_t NB = (size_t)MROWS * HEAD;
    unsigned short* qw  = (unsigned short*)d_ws;
    unsigned short* kw  = qw + NB;
    unsigned short* vtw = kw + NB;
    unsigned short* Wb  = vtw + NB;                       // 192 x 1040 bf16
    float* biasAll = (float*)(Wb + (size_t)NCOL * WST);
    float* mpart   = biasAll + 192;

    const size_t base = 3 * NB * 2 + (size_t)NCOL * WST * 2 + 192 * 4;
    const size_t per  = (size_t)MROWS * 8 + NB * 4;
    int KS = 1;
    if      (ws_size >= base + 4 * per) KS = 4;
    else if (ws_size >= base + 2 * per) KS = 2;

    float* lpart = mpart + (size_t)KS * MROWS;
    float* opart = lpart + (size_t)KS * MROWS;

    wconv_kernel<<<dim3(192), 256, 0, stream>>>(wq, bq, wk, bk, wv, bv, Wb, biasAll);
    qkvmm_kernel<<<dim3(MROWS / 32), 256, 0, stream>>>(x, Wb, biasAll, qw, kw, vtw);
    flashmm_kernel<<<dim3(SEQ / QBLK, BATCH, KS), 128, 0, stream>>>(qw, kw, vtw, mask,
                                                                    opart, mpart, lpart, KS);
    combine_kernel<<<dim3(MROWS * 16 / 256), 256, 0, stream>>>(opart, mpart, lpart, out, KS);
}

// Round 16
// 74.356 us; speedup vs baseline: 1.6515x; 1.6515x over previous
//
#include <hip/hip_runtime.h>
#include <math.h>

#define BATCH 4
#define SEQ   4096
#define DIM   1024
#define HEAD  64
#define MROWS (BATCH*SEQ)   // 16384
#define NCOL  192
#define WST   1040          // repacked W row stride (elements)
#define KT    64
#define QBLK  64            // flashmm q-rows per block (proven locality)
#define BK2   64            // qkvmm K-step
#define NIT2  (DIM / BK2)   // 16

typedef __attribute__((ext_vector_type(8))) short short8;
typedef __attribute__((ext_vector_type(4))) float f32x4;

static __device__ __forceinline__ unsigned short f2b(float f) {
    union { float f; unsigned u; } v; v.f = f;
    return (unsigned short)((v.u + 0x7FFFu + ((v.u >> 16) & 1u)) >> 16);
}
// hardware RTNE pack: low16 = bf16(a), high16 = bf16(b)
static __device__ __forceinline__ unsigned cvtpk(float a, float b) {
    unsigned r;
    asm("v_cvt_pk_bf16_f32 %0, %1, %2" : "=v"(r) : "v"(a), "v"(b));
    return r;
}

// ---------------- Kernel 0: weight convert fp32 -> bf16, stride-1040 repack ----------------
#define QSC (0.125f * 1.4426950408889634f)   // fold 1/sqrt(64) * log2(e): exp2 domain
__global__ __launch_bounds__(256) void wconv_kernel(
    const float* __restrict__ wq, const float* __restrict__ bq,
    const float* __restrict__ wk, const float* __restrict__ bk,
    const float* __restrict__ wv, const float* __restrict__ bv,
    unsigned short* __restrict__ Wb, float* __restrict__ biasAll)
{
    int idx = blockIdx.x * 256 + threadIdx.x;
    int e   = idx * 4;
    int row = e >> 10;
    int col = e & 1023;
    const float* src = (row < 64) ? wq : (row < 128) ? wk : wv;
    float s = (row < 64) ? QSC : 1.0f;
    float4 g = *(const float4*)&src[(size_t)(row & 63) * DIM + col];
    ushort4 o;
    o.x = f2b(g.x * s); o.y = f2b(g.y * s); o.z = f2b(g.z * s); o.w = f2b(g.w * s);
    *(ushort4*)&Wb[(size_t)row * WST + col] = o;
    if (idx < 192) {
        const float* bs = (idx < 64) ? bq : (idx < 128) ? bk : bv;
        biasAll[idx] = bs[idx & 63] * ((idx < 64) ? QSC : 1.0f);
    }
}

// ---------------- Kernel 1: fused QKV projection (R13-exact, best profiled: 40.6us) -------
__global__ __launch_bounds__(256, 4) void qkvmm_kernel(
    const float* __restrict__ x, const unsigned short* __restrict__ Wb,
    const float* __restrict__ biasAll,
    unsigned short* __restrict__ qout, unsigned short* __restrict__ kout,
    unsigned short* __restrict__ vtout)
{
    __shared__ unsigned short xs[32 * BK2];     // 4 KB
    __shared__ unsigned short ws[NCOL * BK2];   // 24 KB

    const int tid  = threadIdx.x;
    const int m0   = blockIdx.x * 32;
    const int bb   = m0 >> 12;
    const int lane = tid & 63;
    const int w    = tid >> 6;
    const int lr   = lane & 15;
    const int lg   = lane >> 4;
    const int mrow  = (w >> 1) * 16;
    const int nbase = (w & 1) * 6;

    int wrow[6], wc[6];
    #pragma unroll
    for (int j = 0; j < 6; ++j) { int L = j * 256 + tid; wrow[j] = L >> 3; wc[j] = L & 7; }
    const int xr = tid >> 2, xq = tid & 3;

    f32x4 acc[6];
    #pragma unroll
    for (int nt = 0; nt < 6; ++nt) acc[nt] = (f32x4){0.f, 0.f, 0.f, 0.f};

    float4 xg[4];
    short8 wg[6];

    auto LOADR = [&](int ko) {
        if (tid < 128) {
            const float* xp = &x[(size_t)(m0 + xr) * DIM + ko + xq * 16];
            xg[0] = *(const float4*)xp;       xg[1] = *(const float4*)(xp + 4);
            xg[2] = *(const float4*)(xp + 8); xg[3] = *(const float4*)(xp + 12);
        }
        #pragma unroll
        for (int j = 0; j < 6; ++j)
            wg[j] = *(const short8*)&Wb[(size_t)wrow[j] * WST + ko + wc[j] * 8];
    };
    auto WRITE = [&]() {
        if (tid < 128) {
            uint4 c0, c1;
            c0.x = cvtpk(xg[0].x, xg[0].y); c0.y = cvtpk(xg[0].z, xg[0].w);
            c0.z = cvtpk(xg[1].x, xg[1].y); c0.w = cvtpk(xg[1].z, xg[1].w);
            c1.x = cvtpk(xg[2].x, xg[2].y); c1.y = cvtpk(xg[2].z, xg[2].w);
            c1.z = cvtpk(xg[3].x, xg[3].y); c1.w = cvtpk(xg[3].z, xg[3].w);
            *(uint4*)&xs[xr * BK2 + (((2 * xq)     ^ (xr & 7)) * 8)] = c0;
            *(uint4*)&xs[xr * BK2 + (((2 * xq + 1) ^ (xr & 7)) * 8)] = c1;
        }
        #pragma unroll
        for (int j = 0; j < 6; ++j)
            *(short8*)&ws[wrow[j] * BK2 + ((wc[j] ^ (wrow[j] & 7)) * 8)] = wg[j];
    };

    LOADR(0);
    for (int it = 0; it < NIT2; ++it) {
        __syncthreads();
        WRITE();
        __syncthreads();
        if (it + 1 < NIT2) LOADR((it + 1) * BK2);

        __builtin_amdgcn_s_setprio(1);
        #pragma unroll
        for (int h = 0; h < 2; ++h) {
            const int arow = mrow + lr;
            short8 af = *(const short8*)&xs[arow * BK2 + (((h * 4 + lg) ^ (arow & 7)) * 8)];
            #pragma unroll
            for (int nt = 0; nt < 6; ++nt) {
                int n = (nbase + nt) * 16 + lr;
                short8 bf = *(const short8*)&ws[n * BK2 + (((h * 4 + lg) ^ (n & 7)) * 8)];
                acc[nt] = __builtin_amdgcn_mfma_f32_16x16x32_bf16(af, bf, acc[nt], 0, 0, 0);
            }
        }
        __builtin_amdgcn_s_setprio(0);
    }

    #pragma unroll
    for (int nt = 0; nt < 6; ++nt) {
        int gn = (nbase + nt) * 16 + lr;
        float bv_ = biasAll[gn];
        #pragma unroll
        for (int r = 0; r < 4; ++r) {
            int grow = m0 + mrow + lg * 4 + r;
            unsigned short val = f2b(acc[nt][r] + bv_);
            if (gn < 64)       qout[(size_t)grow * HEAD + gn] = val;
            else if (gn < 128) kout[(size_t)grow * HEAD + gn - 64] = val;
            else {
                int t = (m0 & 4095) + mrow + lg * 4 + r;
                vtout[((size_t)bb * HEAD + gn - 128) * SEQ + t] = val;
            }
        }
    }
}

// ---------------- Kernel 2: flash attention — 4-wave proven config ----------------
// grid (SEQ/QBLK, BATCH, KS), block 256 (4 waves). Lane owns q-row lr, keys lg-sliced.
__global__ __launch_bounds__(256, 4) void flashmm_kernel(
    const unsigned short* __restrict__ qb, const unsigned short* __restrict__ kb,
    const unsigned short* __restrict__ vt, const int* __restrict__ mask,
    float* __restrict__ opart, float* __restrict__ mpart, float* __restrict__ lpart,
    int nsplit)
{
    const int b  = blockIdx.y;
    const int t0 = blockIdx.x * QBLK;
    const int z  = blockIdx.z;
    const int tid  = threadIdx.x;
    const int lane = tid & 63;
    const int w    = tid >> 6;
    const int lr = lane & 15;
    const int lg = lane >> 4;
    const int span = SEQ / nsplit;
    const int s_begin = z * span, s_end = s_begin + span;

    __shared__ unsigned short ks_l[KT * HEAD];
    __shared__ unsigned short vt_l[HEAD * KT];
    __shared__ unsigned short ps_l[4][16 * KT];
    __shared__ float mkf[KT];

    const unsigned short* qrow = qb + ((size_t)(b * SEQ + t0 + w * 16 + lr)) * HEAD;
    const short8 qf0 = *(const short8*)(qrow + lg * 8);
    const short8 qf1 = *(const short8*)(qrow + 32 + lg * 8);

    f32x4 acc_o[4];
    #pragma unroll
    for (int nt = 0; nt < 4; ++nt) acc_o[nt] = (f32x4){0.f, 0.f, 0.f, 0.f};
    float m_r = -INFINITY, l_r = 0.f;

    short8 kg[2], vg[2];
    float mgf = 0.f;

    auto LOADR = [&](int st) {
        #pragma unroll
        for (int i = 0; i < 2; ++i) {
            int c   = tid + i * 256;
            int row = c >> 3;
            int h0  = (c & 7) * 8;
            kg[i] = *(const short8*)(kb + ((size_t)(b * SEQ + st + row)) * HEAD + h0);
            vg[i] = *(const short8*)(vt + ((size_t)(b * HEAD + row)) * SEQ + st + h0);
        }
        if (tid < KT) mgf = (mask[(size_t)b * SEQ + st + tid] != 0) ? 0.f : -1e9f;
    };
    auto WRITE = [&]() {
        #pragma unroll
        for (int i = 0; i < 2; ++i) {
            int c   = tid + i * 256;
            int row = c >> 3;
            int h0  = (c & 7) * 8;
            *(short8*)&ks_l[row * HEAD + (h0 ^ ((row & 7) << 3))] = kg[i];
            *(short8*)&vt_l[row * KT + (h0 ^ ((row & 7) << 3))] = vg[i];
        }
        if (tid < KT) mkf[tid] = mgf;
    };

    LOADR(s_begin);
    for (int st = s_begin; st < s_end; st += KT) {
        __syncthreads();
        WRITE();
        __syncthreads();
        if (st + KT < s_end) LOADR(st + KT);

        f32x4 sT[4];
        __builtin_amdgcn_s_setprio(1);
        #pragma unroll
        for (int ct = 0; ct < 4; ++ct) {
            int krow = ct * 16 + lr;
            short8 kf0 = *(const short8*)&ks_l[krow * HEAD + ((lg * 8) ^ ((krow & 7) << 3))];
            short8 kf1 = *(const short8*)&ks_l[krow * HEAD + ((32 + lg * 8) ^ ((krow & 7) << 3))];
            f32x4 zz = (f32x4){0.f, 0.f, 0.f, 0.f};
            zz = __builtin_amdgcn_mfma_f32_16x16x32_bf16(kf0, qf0, zz, 0, 0, 0);
            zz = __builtin_amdgcn_mfma_f32_16x16x32_bf16(kf1, qf1, zz, 0, 0, 0);
            sT[ct] = zz;
        }
        __builtin_amdgcn_s_setprio(0);

        #pragma unroll
        for (int ct = 0; ct < 4; ++ct) {
            f32x4 mb = *(const f32x4*)&mkf[ct * 16 + lg * 4];
            sT[ct][0] += mb[0]; sT[ct][1] += mb[1];
            sT[ct][2] += mb[2]; sT[ct][3] += mb[3];
        }

        float mx = sT[0][0];
        #pragma unroll
        for (int ct = 0; ct < 4; ++ct)
            #pragma unroll
            for (int r = 0; r < 4; ++r) mx = fmaxf(mx, sT[ct][r]);
        mx = fmaxf(mx, __shfl_xor(mx, 16));
        mx = fmaxf(mx, __shfl_xor(mx, 32));

        bool defer = __all(mx <= m_r + 8.f);
        float base = defer ? m_r : fmaxf(m_r, mx);

        float rs = 0.f;
        #pragma unroll
        for (int ct = 0; ct < 4; ++ct)
            #pragma unroll
            for (int r = 0; r < 4; ++r) {
                float p = __builtin_amdgcn_exp2f(sT[ct][r] - base);
                sT[ct][r] = p;
                rs += p;
            }
        rs += __shfl_xor(rs, 16);
        rs += __shfl_xor(rs, 32);

        if (defer) {
            l_r += rs;
        } else {
            float sf = __builtin_amdgcn_exp2f(m_r - base);
            l_r = l_r * sf + rs;
            m_r = base;
            #pragma unroll
            for (int r = 0; r < 4; ++r) {
                float sfr = __shfl(sf, lg * 4 + r);
                #pragma unroll
                for (int nt = 0; nt < 4; ++nt) acc_o[nt][r] *= sfr;
            }
        }

        #pragma unroll
        for (int ct = 0; ct < 4; ++ct) {
            uint2 pk;
            pk.x = cvtpk(sT[ct][0], sT[ct][1]);
            pk.y = cvtpk(sT[ct][2], sT[ct][3]);
            *(uint2*)&ps_l[w][lr * KT + ((ct * 16 + lg * 4) ^ ((lr & 7) << 3))] = pk;
        }

        __builtin_amdgcn_s_setprio(1);
        #pragma unroll
        for (int kk = 0; kk < 2; ++kk) {
            int s0 = kk * 32 + lg * 8;
            short8 pf = *(const short8*)&ps_l[w][lr * KT + (s0 ^ ((lr & 7) << 3))];
            #pragma unroll
            for (int nt = 0; nt < 4; ++nt) {
                int hrow = nt * 16 + lr;
                short8 vf = *(const short8*)&vt_l[hrow * KT + (s0 ^ ((hrow & 7) << 3))];
                acc_o[nt] = __builtin_amdgcn_mfma_f32_16x16x32_bf16(pf, vf, acc_o[nt], 0, 0, 0);
            }
        }
        __builtin_amdgcn_s_setprio(0);
    }

    const size_t rbase = (size_t)z * MROWS + (size_t)b * SEQ + t0 + w * 16;
    const size_t obase = rbase * HEAD;
    #pragma unroll
    for (int nt = 0; nt < 4; ++nt)
        #pragma unroll
        for (int r = 0; r < 4; ++r) {
            int R = lg * 4 + r;
            opart[obase + (size_t)R * HEAD + nt * 16 + lr] = acc_o[nt][r];
        }
    if (lg == 0) {
        mpart[rbase + lr] = m_r;
        lpart[rbase + lr] = l_r;
    }
}

// ---------------- Kernel 3: split combine + normalize (exp2 domain) ----------------
__global__ __launch_bounds__(256) void combine_kernel(
    const float* __restrict__ op, const float* __restrict__ mp,
    const float* __restrict__ lp, float* __restrict__ out, int nsplit)
{
    int idx = blockIdx.x * 256 + threadIdx.x;
    int row = idx >> 4;
    int h4  = (idx & 15) * 4;
    float mstar = -INFINITY;
    for (int s = 0; s < nsplit; ++s)
        mstar = fmaxf(mstar, mp[(size_t)s * MROWS + row]);
    float L = 0.f;
    float ax = 0.f, ay = 0.f, az = 0.f, aw = 0.f;
    for (int s = 0; s < nsplit; ++s) {
        float wgt = __builtin_amdgcn_exp2f(mp[(size_t)s * MROWS + row] - mstar);
        L += lp[(size_t)s * MROWS + row] * wgt;
        float4 o = *(const float4*)&op[((size_t)s * MROWS + row) * HEAD + h4];
        ax += o.x * wgt; ay += o.y * wgt; az += o.z * wgt; aw += o.w * wgt;
    }
    float r = 1.f / L;
    float4 res; res.x = ax * r; res.y = ay * r; res.z = az * r; res.w = aw * r;
    *(float4*)&out[(size_t)row * HEAD + h4] = res;
}

extern "C" void kernel_launch(void* const* d_in, const int* in_sizes, int n_in,
                              void* d_out, int out_size, void* d_ws, size_t ws_size,
                              hipStream_t stream) {
    const float* x    = (const float*)d_in[0];
    const int*   mask = (const int*)d_in[1];
    const float* wq   = (const float*)d_in[2];
    const float* bq   = (const float*)d_in[3];
    const float* wk   = (const float*)d_in[4];
    const float* bk   = (const float*)d_in[5];
    const float* wv   = (const float*)d_in[6];
    const float* bv   = (const float*)d_in[7];
    float* out = (float*)d_out;
    (void)in_sizes; (void)n_in; (void)out_size;

    const size_t NB = (size_t)MROWS * HEAD;
    unsigned short* qw  = (unsigned short*)d_ws;
    unsigned short* kw  = qw + NB;
    unsigned short* vtw = kw + NB;
    unsigned short* Wb  = vtw + NB;                       // 192 x 1040 bf16
    float* biasAll = (float*)(Wb + (size_t)NCOL * WST);
    float* mpart   = biasAll + 192;

    const size_t base = 3 * NB * 2 + (size_t)NCOL * WST * 2 + 192 * 4;
    const size_t per  = (size_t)MROWS * 8 + NB * 4;
    int KS = 1;
    if      (ws_size >= base + 4 * per) KS = 4;
    else if (ws_size >= base + 2 * per) KS = 2;

    float* lpart = mpart + (size_t)KS * MROWS;
    float* opart = lpart + (size_t)KS * MROWS;

    wconv_kernel<<<dim3(192), 256, 0, stream>>>(wq, bq, wk, bk, wv, bv, Wb, biasAll);
    qkvmm_kernel<<<dim3(MROWS / 32), 256, 0, stream>>>(x, Wb, biasAll, qw, kw, vtw);
    flashmm_kernel<<<dim3(SEQ / QBLK, BATCH, KS), 256, 0, stream>>>(qw, kw, vtw, mask,
                                                                    opart, mpart, lpart, KS);
    combine_kernel<<<dim3(MROWS * 16 / 256), 256, 0, stream>>>(opart, mpart, lpart, out, KS);
}